// Round 14
// baseline (135.936 us; speedup 1.0000x reference)
//
#include <hip/hip_runtime.h>
#include <hip/hip_fp8.h>
#include <math.h>

#define BSZ   8192
#define NCLS  57
#define DIM   256
#define NTASK 57
#define INV_T (1.0f/0.07f)
#define GBM   64                 // row tiles (128 rows each)
#define GBN   32                 // col tiles (256 cols each)
#define NTILE (GBM * GBN)        // 2048

typedef float f32x4 __attribute__((ext_vector_type(4)));
typedef long  lgx2  __attribute__((ext_vector_type(2)));

// async global->LDS, 16B per lane; l must be wave-uniform base (HW adds lane*16)
__device__ __forceinline__ void gload_lds16(const void* g, void* l) {
    __builtin_amdgcn_global_load_lds(
        (const __attribute__((address_space(1))) unsigned int*)g,
        (__attribute__((address_space(3))) unsigned int*)l, 16, 0, 0);
}

// ---- kernel 1: fused logits stats + normalize->fp8 (K-interleaved) + zero-init -----
__global__ __launch_bounds__(256) void k_prep(
        const float* __restrict__ logits, const float* __restrict__ emb,
        const int* __restrict__ labels, float* __restrict__ u,
        float* __restrict__ cls_part, unsigned char* __restrict__ e,
        int* __restrict__ hdr) {
    __shared__ float scls[4];
    int wave = threadIdx.x >> 6;
    int lane = threadIdx.x & 63;
    int row  = blockIdx.x * 4 + wave;

    float v = (lane < NCLS) ? logits[row * NCLS + lane] : -3.0e38f;
    float m = v;
    #pragma unroll
    for (int s = 1; s < 64; s <<= 1) m = fmaxf(m, __shfl_xor(m, s));
    float ex = (lane < NCLS) ? __expf(v - m) : 0.0f;
    float se = ex;
    #pragma unroll
    for (int s = 1; s < 64; s <<= 1) se += __shfl_xor(se, s);
    float lse = m + logf(se);
    float p = ex / se;
    float term = (lane < NCLS) ? p * logf(p + 1e-8f) : 0.0f;
    float ent = term;
    #pragma unroll
    for (int s = 1; s < 64; s <<= 1) ent += __shfl_xor(ent, s);
    ent = -ent;
    int lab = labels[row];
    float vl = __shfl(v, lab);
    float cls = lse - vl;

    const float4* src = reinterpret_cast<const float4*>(emb + (size_t)row * DIM);
    float4 x = src[lane];
    float ss = x.x*x.x + x.y*x.y + x.z*x.z + x.w*x.w;
    #pragma unroll
    for (int s = 1; s < 64; s <<= 1) ss += __shfl_xor(ss, s);
    float sc = 1.0f / fmaxf(sqrtf(ss), 1e-12f);
    __hip_fp8_e4m3 f0(x.x * sc), f1(x.y * sc), f2(x.z * sc), f3(x.w * sc);
    uchar4 o;
    o.x = *reinterpret_cast<unsigned char*>(&f0);
    o.y = *reinterpret_cast<unsigned char*>(&f1);
    o.z = *reinterpret_cast<unsigned char*>(&f2);
    o.w = *reinterpret_cast<unsigned char*>(&f3);
    int kp = (lane >> 4) * 64 + ((lane >> 1) & 3) * 16 + ((lane >> 3) & 1) * 8
           + (lane & 1) * 4;
    *reinterpret_cast<uchar4*>(e + (size_t)row * DIM + kp) = o;

    if (lane == 0) {
        u[row] = ent / 4.04305127f;      // log(57)
        scls[wave] = cls;
    }
    // zero tickets (32 stripe + 1 global) + contr_total  (kernel boundary -> visible)
    if (blockIdx.x == 0 && threadIdx.x < 34) hdr[threadIdx.x] = 0;
    __syncthreads();
    if (threadIdx.x == 0) cls_part[blockIdx.x] = scls[0] + scls[1] + scls[2] + scls[3];
}

// ---- epilogue accumulate, specialized on diagonal presence -------------------------
template<bool HD>
__device__ __forceinline__ void epi_accum(
        const f32x4 (&acc)[4][4], const unsigned char* ts, const int* ctb,
        int m0, int cbase, int h, int g, int lr,
        float (&T)[4], float (&P)[4], float (&S)[4]) {
    #pragma unroll
    for (int m = 0; m < 4; ++m) {
        unsigned rt4 = *reinterpret_cast<const unsigned*>(&ts[h * 64 + m * 16 + g * 4]);
        #pragma unroll
        for (int r = 0; r < 4; ++r) {
            int rt = (rt4 >> (8 * r)) & 255;
            #pragma unroll
            for (int f = 0; f < 4; ++f) {
                float sv = acc[m][f][r] * INV_T;
                float ev = __expf(sv);
                bool keep = true;
                if (HD)
                    keep = (m0 + h * 64 + m * 16 + g * 4 + r) != (cbase + f * 16 + lr);
                bool eq = (rt == ctb[f]) && keep;
                T[f] += keep ? ev : 0.0f;
                P[f] += eq ? ev : 0.0f;
                S[f] += eq ? sv : 0.0f;
            }
        }
    }
}

// ---- kernel 2: full sim matrix + unique-writer partials + stripe-ticket finalize ---
// GEMM core = R12 (JIT B, <=128 unified regs, 2 blocks/CU). Epilogue: R12 unique-slot
// stores (as relaxed AGENT atomic stores for cross-XCD visibility; ~1.5M stores, no
// RMW). Per-bn ticket: 64th block of a stripe reduces 64 bm-partials for its 256
// cols (192 KB, coalesced, overlaps remaining GEMM blocks), adds stripe contr to
// contr_total; 32nd stripe-winner does the final combine. Two graph nodes total.
__global__ __launch_bounds__(512, 2) void k_negsum(
        const unsigned char* __restrict__ E, const int* __restrict__ tasks,
        float* __restrict__ partial, const float* __restrict__ u,
        const float* __restrict__ cls_part, int* __restrict__ hdr,
        float* __restrict__ out) {
    __shared__ unsigned char Asm[128 * 256];   // 32 KB
    __shared__ unsigned char ts[128];
    __shared__ float scr[3][256];
    __shared__ int winflag, finflag;
    __shared__ int hist[NTASK];
    __shared__ float wsT[256], wsP[256], wsS[256];
    __shared__ float redf[8]; __shared__ long long redn[8];

    int* ticketbn = hdr;                 // [32]
    int* ticket2  = hdr + 32;
    float* contr_total = (float*)(hdr + 33);

    // XCD swizzle (2048 % 8 == 0 -> bijective)
    int b = (blockIdx.x & 7) * (NTILE / 8) + (blockIdx.x >> 3);
    int bm = b >> 5, bn = b & 31;
    int m0 = bm * 128, n0 = bn * 256;
    bool hasdiag = (bn == (bm >> 1));

    int tid = threadIdx.x;
    int w = tid >> 6, lane = tid & 63;
    int h = w >> 2, cg = w & 3;
    int g = lane >> 4, lr = lane & 15;
    int cbase = n0 + cg * 64;
    const unsigned char* bp = E + (size_t)(cbase + lr) * DIM + g * 16;

    lgx2 bc[4];
    #pragma unroll
    for (int f = 0; f < 4; ++f)
        bc[f] = *reinterpret_cast<const lgx2*>(bp + (size_t)f * 16 * DIM);

    #pragma unroll
    for (int it = 0; it < 4; ++it) {
        int flat = it * 512 + tid;
        int row = flat >> 4, kb = flat & 15;
        int kbs = kb ^ (row & 7);
        gload_lds16(E + (size_t)(m0 + row) * DIM + kbs * 16,
                    Asm + (size_t)(it * 512 + w * 64) * 16);
    }
    if (tid < 128) ts[tid] = (unsigned char)tasks[m0 + tid];
    __syncthreads();

    f32x4 acc[4][4] = {};
    #pragma unroll 1
    for (int t = 0; t < 4; ++t) {
        lgx2 bn_[4];
        if (t < 3) {
            #pragma unroll
            for (int f = 0; f < 4; ++f)
                bn_[f] = *reinterpret_cast<const lgx2*>(
                    bp + (size_t)f * 16 * DIM + (t + 1) * 64);
        }
        lgx2 a[4];
        #pragma unroll
        for (int m = 0; m < 4; ++m)
            a[m] = *reinterpret_cast<const lgx2*>(
                Asm + (size_t)(h * 64 + m * 16 + lr) * 256
                    + (((t * 4 + g) ^ (lr & 7)) * 16));
        #pragma unroll
        for (int m = 0; m < 4; ++m)
            #pragma unroll
            for (int f = 0; f < 4; ++f) {
                acc[m][f] = __builtin_amdgcn_mfma_f32_16x16x32_fp8_fp8(
                    a[m][0], bc[f][0], acc[m][f], 0, 0, 0);
                acc[m][f] = __builtin_amdgcn_mfma_f32_16x16x32_fp8_fp8(
                    a[m][1], bc[f][1], acc[m][f], 0, 0, 0);
            }
        if (t < 3) {
            #pragma unroll
            for (int f = 0; f < 4; ++f) bc[f] = bn_[f];
        }
    }

    int ctb[4];
    #pragma unroll
    for (int f = 0; f < 4; ++f) ctb[f] = tasks[cbase + f * 16 + lr];
    float T[4] = {}, P[4] = {}, S[4] = {};
    if (hasdiag) epi_accum<true >(acc, ts, ctb, m0, cbase, h, g, lr, T, P, S);
    else         epi_accum<false>(acc, ts, ctb, m0, cbase, h, g, lr, T, P, S);

    #pragma unroll
    for (int f = 0; f < 4; ++f) {
        T[f] += __shfl_xor(T[f], 16); T[f] += __shfl_xor(T[f], 32);
        P[f] += __shfl_xor(P[f], 16); P[f] += __shfl_xor(P[f], 32);
        S[f] += __shfl_xor(S[f], 16); S[f] += __shfl_xor(S[f], 32);
    }
    if (h == 1 && g == 0) {
        #pragma unroll
        for (int f = 0; f < 4; ++f) {
            int c = cg * 64 + f * 16 + lr;
            scr[0][c] = T[f]; scr[1][c] = P[f]; scr[2][c] = S[f];
        }
    }
    __syncthreads();
    if (h == 0 && g == 0) {
        #pragma unroll
        for (int f = 0; f < 4; ++f) {
            int c = cg * 64 + f * 16 + lr;
            size_t sl = (size_t)bm * BSZ + n0 + c;
            __hip_atomic_store(&partial[sl], T[f] + scr[0][c],
                               __ATOMIC_RELAXED, __HIP_MEMORY_SCOPE_AGENT);
            __hip_atomic_store(&partial[(size_t)GBM * BSZ + sl], P[f] + scr[1][c],
                               __ATOMIC_RELAXED, __HIP_MEMORY_SCOPE_AGENT);
            __hip_atomic_store(&partial[(size_t)2 * GBM * BSZ + sl], S[f] + scr[2][c],
                               __ATOMIC_RELAXED, __HIP_MEMORY_SCOPE_AGENT);
        }
    }

    // ---- stripe ticket: 64th block of this bn reduces the stripe ----
    __syncthreads();                     // all stores issued & drained
    if (tid == 0) {
        __threadfence();                 // release partials
        winflag = (__hip_atomic_fetch_add(&ticketbn[bn], 1, __ATOMIC_ACQ_REL,
                                          __HIP_MEMORY_SCOPE_AGENT) == GBM - 1);
    }
    __syncthreads();
    if (!winflag) return;
    __threadfence();                     // acquire all stripe partials

    if (tid < NTASK) hist[tid] = 0;
    __syncthreads();
    for (int i = tid; i < BSZ; i += 512) atomicAdd(&hist[tasks[i]], 1);
    __syncthreads();

    {   // reduce 64 bm-partials for cols [n0, n0+256): 2 threads per column
        int jloc = tid & 255;
        int j = n0 + jloc;
        int bm0 = (tid >> 8) * 32;
        float Ts = 0.0f, Ps = 0.0f, Ss = 0.0f;
        #pragma unroll 8
        for (int q = 0; q < 32; ++q) {
            size_t sl = (size_t)(bm0 + q) * BSZ + j;
            Ts += __hip_atomic_load(&partial[sl], __ATOMIC_RELAXED, __HIP_MEMORY_SCOPE_AGENT);
            Ps += __hip_atomic_load(&partial[(size_t)GBM * BSZ + sl], __ATOMIC_RELAXED, __HIP_MEMORY_SCOPE_AGENT);
            Ss += __hip_atomic_load(&partial[(size_t)2 * GBM * BSZ + sl], __ATOMIC_RELAXED, __HIP_MEMORY_SCOPE_AGENT);
        }
        if (tid >= 256) { wsT[jloc] = Ts; wsP[jloc] = Ps; wsS[jloc] = Ss; }
        __syncthreads();
        float v = 0.0f;
        if (tid < 256) {
            Ts += wsT[jloc]; Ps += wsP[jloc]; Ss += wsS[jloc];
            int c = hist[tasks[j]];
            if (c >= 2 && c < BSZ) {
                float C = (Ts - Ps) + 1e-8f;
                v = u[j] * ((float)(c - 1) * logf(C) + Ps / C - Ss);
            }
        }
        #pragma unroll
        for (int s = 1; s < 64; s <<= 1) v += __shfl_xor(v, s);
        if (lane == 0) redf[w] = v;
        __syncthreads();
        if (tid == 0) {
            float sv2 = 0.0f;
            #pragma unroll
            for (int q = 0; q < 4; ++q) sv2 += redf[q];   // waves 4..7 had tid>=256
            atomicAdd(contr_total, sv2);
            __threadfence();
            finflag = (__hip_atomic_fetch_add(ticket2, 1, __ATOMIC_ACQ_REL,
                                              __HIP_MEMORY_SCOPE_AGENT) == GBN - 1);
        }
    }
    __syncthreads();
    if (!finflag) return;
    __threadfence();                     // acquire all stripe contr adds

    // ---- final combine (whole block participates) ----
    float cl = 0.0f;
    for (int q = tid; q < BSZ / 4; q += 512) cl += cls_part[q];
    long long cn = 0;
    if (tid < NTASK) {
        int cc = hist[tid];
        if (cc >= 2 && cc < BSZ) cn = (long long)cc * (cc - 1);
    }
    #pragma unroll
    for (int s = 1; s < 64; s <<= 1) { cl += __shfl_xor(cl, s); cn += __shfl_xor(cn, s); }
    if (lane == 0) { redf[w] = cl; redn[w] = cn; }
    __syncthreads();
    if (tid == 0) {
        float ct = 0.0f; long long cnt = 0;
        #pragma unroll
        for (int q = 0; q < 8; ++q) { ct += redf[q]; cnt += redn[q]; }
        float con = __hip_atomic_load(contr_total, __ATOMIC_ACQUIRE,
                                      __HIP_MEMORY_SCOPE_AGENT);
        out[0] = 0.7f * (ct / (float)BSZ)
               + 0.3f * (cnt > 0 ? con / (float)cnt : 0.0f);
    }
}

extern "C" void kernel_launch(void* const* d_in, const int* in_sizes, int n_in,
                              void* d_out, int out_size, void* d_ws, size_t ws_size,
                              hipStream_t stream) {
    const float* logits = (const float*)d_in[0];
    const float* emb    = (const float*)d_in[1];
    const int*   labels = (const int*)d_in[2];
    const int*   tasks  = (const int*)d_in[3];
    float* out = (float*)d_out;

    char* ws = (char*)d_ws;
    // layout (4B units):
    // hdr[64]: [0..31]=ticketbn [32]=ticket2 [33]=contr_total
    // u[BSZ], cls_part[2048], partial[3*GBM*BSZ] (6 MB), E fp8[BSZ*DIM] (2 MB)
    int*   hdr      = (int*)ws;
    float* u        = (float*)ws + 64;
    float* cls_part = u + BSZ;
    float* partial  = cls_part + 2048;
    unsigned char* e = (unsigned char*)(partial + (size_t)3 * GBM * BSZ);

    // 2 nodes; k_prep zero-inits tickets + contr_total (no memset node)
    k_prep  <<<BSZ / 4, 256, 0, stream>>>(logits, emb, labels, u, cls_part, e, hdr);
    k_negsum<<<NTILE,   512, 0, stream>>>(e, tasks, partial, u, cls_part, hdr, out);
}

// Round 15
// 87.076 us; speedup vs baseline: 1.5611x; 1.5611x over previous
//
#include <hip/hip_runtime.h>
#include <hip/hip_fp8.h>
#include <math.h>

#define BSZ   8192
#define NCLS  57
#define DIM   256
#define NTASK 57
#define INV_T (1.0f/0.07f)
#define CPB   32                 // columns per block
#define NBLK  (BSZ / CPB)        // 256 blocks

typedef float f32x4 __attribute__((ext_vector_type(4)));
typedef long  lgx2  __attribute__((ext_vector_type(2)));

// ---- kernel 1: fused logits stats + normalize->fp8 (K-interleaved) + hdr zero ------
// fp8 K-layout: k' = (ks>>1)*64 + g*16 + (ks&1)*8 + b for original k = ks*32+g*8+b:
// makes all fragment reads pure b128 (verified R9/R10).
__global__ __launch_bounds__(256) void k_prep(
        const float* __restrict__ logits, const float* __restrict__ emb,
        const int* __restrict__ labels, float* __restrict__ u,
        float* __restrict__ cls_part, unsigned char* __restrict__ e,
        int* __restrict__ hdr) {
    __shared__ float scls[4];
    int wave = threadIdx.x >> 6;
    int lane = threadIdx.x & 63;
    int row  = blockIdx.x * 4 + wave;

    float v = (lane < NCLS) ? logits[row * NCLS + lane] : -3.0e38f;
    float m = v;
    #pragma unroll
    for (int s = 1; s < 64; s <<= 1) m = fmaxf(m, __shfl_xor(m, s));
    float ex = (lane < NCLS) ? __expf(v - m) : 0.0f;
    float se = ex;
    #pragma unroll
    for (int s = 1; s < 64; s <<= 1) se += __shfl_xor(se, s);
    float lse = m + logf(se);
    float p = ex / se;
    float term = (lane < NCLS) ? p * logf(p + 1e-8f) : 0.0f;
    float ent = term;
    #pragma unroll
    for (int s = 1; s < 64; s <<= 1) ent += __shfl_xor(ent, s);
    ent = -ent;
    int lab = labels[row];
    float vl = __shfl(v, lab);
    float cls = lse - vl;

    const float4* src = reinterpret_cast<const float4*>(emb + (size_t)row * DIM);
    float4 x = src[lane];
    float ss = x.x*x.x + x.y*x.y + x.z*x.z + x.w*x.w;
    #pragma unroll
    for (int s = 1; s < 64; s <<= 1) ss += __shfl_xor(ss, s);
    float sc = 1.0f / fmaxf(sqrtf(ss), 1e-12f);
    __hip_fp8_e4m3 f0(x.x * sc), f1(x.y * sc), f2(x.z * sc), f3(x.w * sc);
    uchar4 o;
    o.x = *reinterpret_cast<unsigned char*>(&f0);
    o.y = *reinterpret_cast<unsigned char*>(&f1);
    o.z = *reinterpret_cast<unsigned char*>(&f2);
    o.w = *reinterpret_cast<unsigned char*>(&f3);
    int kp = (lane >> 4) * 64 + ((lane >> 1) & 3) * 16 + ((lane >> 3) & 1) * 8
           + (lane & 1) * 4;
    *reinterpret_cast<uchar4*>(e + (size_t)row * DIM + kp) = o;

    if (lane == 0) {
        u[row] = ent / 4.04305127f;      // log(57)
        scls[wave] = cls;
    }
    if (blockIdx.x == 0 && threadIdx.x < 2) hdr[threadIdx.x] = 0;  // ticket, contr
    __syncthreads();
    if (threadIdx.x == 0) cls_part[blockIdx.x] = scls[0] + scls[1] + scls[2] + scls[3];
}

// ---- fold: exp + task masks into per-lane column accumulators ----------------------
template<bool HD>
__device__ __forceinline__ void fold2(
        const f32x4& a0, const f32x4& a1, unsigned rt4, int rb, int c0, int g, int lr,
        int ctask0, int ctask1,
        float& T0, float& P0, float& S0, float& T1, float& P1, float& S1) {
    #pragma unroll
    for (int r = 0; r < 4; ++r) {
        int rt = (rt4 >> (8 * r)) & 255;
        int row = rb + g * 4 + r;
        {
            float sv = a0[r] * INV_T, ev = __expf(sv);
            bool keep = !HD || (row != c0 + lr);
            bool eq = (rt == ctask0) && keep;
            T0 += keep ? ev : 0.0f; P0 += eq ? ev : 0.0f; S0 += eq ? sv : 0.0f;
        }
        {
            float sv = a1[r] * INV_T, ev = __expf(sv);
            bool keep = !HD || (row != c0 + 16 + lr);
            bool eq = (rt == ctask1) && keep;
            T1 += keep ? ev : 0.0f; P1 += eq ? ev : 0.0f; S1 += eq ? sv : 0.0f;
        }
    }
}

// ---- kernel 2: column-ownership streaming GEMM + in-block finalize -----------------
// Block owns cols [c0, c0+32); 16 waves each stream 512 rows (32 row-tiles of 16).
// B: 32 cols x K=256 in 32 VGPR. A row-tiles: direct global b128 loads (E is 2 MB ->
// L2-resident per XCD), double-buffered. Per MFMA output the exp/mask fold goes to
// per-lane register T/P/S of the lane's OWN column (reduction is lane-local; only a
// 2-shfl cross-g butterfly + 96-float LDS combine at the end). Task histogram built
// in-block from LDS (identical in all blocks). One atomicAdd(contr)/block + ticket.
// No partial buffers, no fences-for-data, no cross-block data flow except 2 scalars.
__global__ __launch_bounds__(1024, 4) void k_negsum(
        const unsigned char* __restrict__ E, const int* __restrict__ tasks,
        const float* __restrict__ u, const float* __restrict__ cls_part,
        int* __restrict__ hdr, float* __restrict__ out) {
    __shared__ unsigned char ts8[BSZ];   // all row tasks, 8 KB
    __shared__ int hist[NTASK];
    __shared__ float lT[CPB], lP[CPB], lS[CPB];
    __shared__ int lastflag;
    __shared__ float redf[16]; __shared__ long long redn[16];

    int* ticket = hdr;
    float* contr_total = (float*)(hdr + 1);

    int tid = threadIdx.x;
    int w = tid >> 6, lane = tid & 63;
    int g = lane >> 4, lr = lane & 15;
    int c0 = blockIdx.x * CPB;

    // ---- B: 32 cols, full K, in regs (8 x b128 = 32 VGPR) ----
    lgx2 B0[4], B1[4];
    #pragma unroll
    for (int t = 0; t < 4; ++t) {
        B0[t] = *reinterpret_cast<const lgx2*>(
            E + (size_t)(c0 + lr) * DIM + t * 64 + g * 16);
        B1[t] = *reinterpret_cast<const lgx2*>(
            E + (size_t)(c0 + 16 + lr) * DIM + t * 64 + g * 16);
    }

    if (tid < CPB) { lT[tid] = 0.0f; lP[tid] = 0.0f; lS[tid] = 0.0f; }
    if (tid < NTASK) hist[tid] = 0;
    __syncthreads();
    for (int i = tid; i < BSZ; i += 1024) {
        int tv = tasks[i];
        ts8[i] = (unsigned char)tv;
        atomicAdd(&hist[tv], 1);         // LDS atomics: ~0.3us, amortized
    }
    __syncthreads();

    int ctask0 = ts8[c0 + lr];
    int ctask1 = ts8[c0 + 16 + lr];

    // ---- stream 512 rows per wave, 32 row-tiles, A double-buffered ----
    int rbase = w * 512;
    const unsigned char* ap = E + (size_t)(rbase + lr) * DIM + g * 16;
    lgx2 Ac[4], An[4];
    #pragma unroll
    for (int t = 0; t < 4; ++t) Ac[t] = *reinterpret_cast<const lgx2*>(ap + t * 64);

    float T0 = 0, P0 = 0, S0 = 0, T1 = 0, P1 = 0, S1 = 0;
    #pragma unroll 1
    for (int it = 0; it < 32; ++it) {
        if (it < 31) {
            const unsigned char* apn = ap + (size_t)(it + 1) * 16 * DIM;
            #pragma unroll
            for (int t = 0; t < 4; ++t)
                An[t] = *reinterpret_cast<const lgx2*>(apn + t * 64);
        }
        f32x4 a0 = {}, a1 = {};
        #pragma unroll
        for (int t = 0; t < 4; ++t) {
            a0 = __builtin_amdgcn_mfma_f32_16x16x32_fp8_fp8(Ac[t][0], B0[t][0], a0, 0, 0, 0);
            a0 = __builtin_amdgcn_mfma_f32_16x16x32_fp8_fp8(Ac[t][1], B0[t][1], a0, 0, 0, 0);
            a1 = __builtin_amdgcn_mfma_f32_16x16x32_fp8_fp8(Ac[t][0], B1[t][0], a1, 0, 0, 0);
            a1 = __builtin_amdgcn_mfma_f32_16x16x32_fp8_fp8(Ac[t][1], B1[t][1], a1, 0, 0, 0);
        }
        int rb = rbase + it * 16;
        unsigned rt4 = *reinterpret_cast<const unsigned*>(&ts8[rb + g * 4]);
        bool hd = (rb < c0 + CPB) && (rb + 16 > c0);   // wave-uniform branch
        if (hd) fold2<true >(a0, a1, rt4, rb, c0, g, lr, ctask0, ctask1,
                             T0, P0, S0, T1, P1, S1);
        else    fold2<false>(a0, a1, rt4, rb, c0, g, lr, ctask0, ctask1,
                             T0, P0, S0, T1, P1, S1);
        #pragma unroll
        for (int t = 0; t < 4; ++t) Ac[t] = An[t];
    }

    // ---- cross-g butterfly (2 shfl each), then LDS combine across 16 waves ----
    T0 += __shfl_xor(T0, 16); T0 += __shfl_xor(T0, 32);
    P0 += __shfl_xor(P0, 16); P0 += __shfl_xor(P0, 32);
    S0 += __shfl_xor(S0, 16); S0 += __shfl_xor(S0, 32);
    T1 += __shfl_xor(T1, 16); T1 += __shfl_xor(T1, 32);
    P1 += __shfl_xor(P1, 16); P1 += __shfl_xor(P1, 32);
    S1 += __shfl_xor(S1, 16); S1 += __shfl_xor(S1, 32);
    if (g == 0) {
        atomicAdd(&lT[lr], T0);      atomicAdd(&lP[lr], P0);      atomicAdd(&lS[lr], S0);
        atomicAdd(&lT[16 + lr], T1); atomicAdd(&lP[16 + lr], P1); atomicAdd(&lS[16 + lr], S1);
    }
    __syncthreads();

    // ---- per-column contr for this block's 32 cols; one global atomicAdd ----
    if (tid < CPB) {
        int j = c0 + tid;
        int c = hist[ts8[j]];
        float v = 0.0f;
        if (c >= 2 && c < BSZ) {
            float C = (lT[tid] - lP[tid]) + 1e-8f;
            v = u[j] * ((float)(c - 1) * logf(C) + lP[tid] / C - lS[tid]);
        }
        #pragma unroll
        for (int s = 1; s < 32; s <<= 1) v += __shfl_xor(v, s);
        if (tid == 0) {
            atomicAdd(contr_total, v);
            __threadfence();
            lastflag = (__hip_atomic_fetch_add(ticket, 1, __ATOMIC_ACQ_REL,
                                               __HIP_MEMORY_SCOPE_AGENT) == NBLK - 1);
        }
    }
    __syncthreads();
    if (!lastflag) return;
    __threadfence();                     // acquire: all blocks' contr adds visible

    // ---- final combine (last block) ----
    float cl = 0.0f;
    for (int q = tid; q < BSZ / 4; q += 1024) cl += cls_part[q];
    long long cn = 0;
    if (tid < NTASK) {
        int cc = hist[tid];
        if (cc >= 2 && cc < BSZ) cn = (long long)cc * (cc - 1);
    }
    #pragma unroll
    for (int s = 1; s < 64; s <<= 1) { cl += __shfl_xor(cl, s); cn += __shfl_xor(cn, s); }
    if (lane == 0) { redf[w] = cl; redn[w] = cn; }
    __syncthreads();
    if (tid == 0) {
        float ct = 0.0f; long long cnt = 0;
        #pragma unroll
        for (int q = 0; q < 16; ++q) { ct += redf[q]; cnt += redn[q]; }
        float con = __hip_atomic_load(contr_total, __ATOMIC_ACQUIRE,
                                      __HIP_MEMORY_SCOPE_AGENT);
        out[0] = 0.7f * (ct / (float)BSZ)
               + 0.3f * (cnt > 0 ? con / (float)cnt : 0.0f);
    }
}

extern "C" void kernel_launch(void* const* d_in, const int* in_sizes, int n_in,
                              void* d_out, int out_size, void* d_ws, size_t ws_size,
                              hipStream_t stream) {
    const float* logits = (const float*)d_in[0];
    const float* emb    = (const float*)d_in[1];
    const int*   labels = (const int*)d_in[2];
    const int*   tasks  = (const int*)d_in[3];
    float* out = (float*)d_out;

    char* ws = (char*)d_ws;
    // layout (4B units): hdr[64]: [0]=ticket [1]=contr_total
    // u[BSZ], cls_part[2048], E fp8[BSZ*DIM] (2 MB)
    int*   hdr      = (int*)ws;
    float* u        = (float*)ws + 64;
    float* cls_part = u + BSZ;
    unsigned char* e = (unsigned char*)(cls_part + 2048);

    // 2 nodes; k_prep zero-inits ticket + contr_total
    k_prep  <<<BSZ / 4, 256,  0, stream>>>(logits, emb, labels, u, cls_part, e, hdr);
    k_negsum<<<NBLK,    1024, 0, stream>>>(e, tasks, u, cls_part, hdr, out);
}